// Round 2
// baseline (1240.143 us; speedup 1.0000x reference)
//
#include <hip/hip_runtime.h>
#include <hip/hip_bf16.h>
#include <math.h>

// FutureLSTM: B=64,E=128 -> M=8192 independent rows; F=1024; H=512; 4H=2048; D=8 sequential steps.
// ALL inputs/outputs are fp32 (reference dtypes). We convert to bf16 for MFMA; 2% absmax threshold.
#define M_TOT 8192
#define FDIM  1024
#define HDIM  512
#define DSTEPS 8
#define BM 64
#define BK 32

typedef __attribute__((ext_vector_type(8))) short short8;
typedef __attribute__((ext_vector_type(4))) float f32x4;

#define GLOAD_LDS16(gsrc, ldst)                                                        \
    __builtin_amdgcn_global_load_lds(                                                  \
        (__attribute__((address_space(1))) void*)(void*)(gsrc),                        \
        (__attribute__((address_space(3))) void*)(ldst), 16, 0, 0)

__device__ __forceinline__ unsigned short f2bf(float f) {
    // round-to-nearest-even fp32 -> bf16 (inputs are finite; no NaN handling needed)
    unsigned u = __float_as_uint(f);
    return (unsigned short)((u + 0x7FFFu + ((u >> 16) & 1u)) >> 16);
}
__device__ __forceinline__ float sigm(float x) {
    return __builtin_amdgcn_rcpf(1.0f + __expf(-x));  // saturates cleanly at 0/1
}
__device__ __forceinline__ float tanh_(float x) {
    // tanh = 1 - 2/(1+e^{2x}); exp overflow -> rcp(inf)=0 -> 1; underflow -> -1. No NaN.
    return 1.0f - 2.0f * __builtin_amdgcn_rcpf(1.0f + __expf(2.0f * x));
}

// gates = A@Wih^T + h@Whh^T + bias, fused LSTM pointwise -> cbuf (fp32), hout (bf16).
// Block tile: 64 rows x 64 hidden cols x all 4 gates. Wave w owns hidden cols w*16..+15, so each
// lane privately holds i/f/g/o for its (row,col) -> pointwise fuses with zero cross-lane traffic.
__global__ __launch_bounds__(256) void gates_kernel(
    const float* __restrict__ Afp,            // fp32: x (ld=1024) or d_out slice (ld=8192)
    int ldA,
    const __hip_bfloat16* __restrict__ hin,   // [8192,512] bf16
    const __hip_bfloat16* __restrict__ Wihb,  // [2048,1024] bf16
    const __hip_bfloat16* __restrict__ Whhb,  // [2048,512] bf16
    const float* __restrict__ bias,           // [2048] fp32 (b_ih+b_hh)
    float* __restrict__ cbuf,                 // [8192,512] fp32 persistent
    __hip_bfloat16* __restrict__ hout,        // [8192,512] bf16
    int first)
{
    __shared__ __align__(16) __hip_bfloat16 sA[BM * BK];        // 4 KB
    __shared__ __align__(16) __hip_bfloat16 sB[4 * BM * BK];    // 16 KB (4 gate tiles)

    const int t    = threadIdx.x;
    const int wave = t >> 6;
    const int lane = t & 63;
    const int m0   = blockIdx.x * BM;
    const int j0   = blockIdx.y * 64;

    f32x4 acc[4][4];  // [gate][mi]
    #pragma unroll
    for (int g = 0; g < 4; ++g)
        #pragma unroll
        for (int mi = 0; mi < 4; ++mi) acc[g][mi] = (f32x4)(0.0f);

    const int row_ld = t >> 2;  // 0..63: tile row this thread stages
    const int kh     = t & 3;   // which 8-elem chunk of the 32-wide K slab
    const int fr     = lane & 15;
    const int quad   = lane >> 4;

    for (int phase = 0; phase < 2; ++phase) {
        if (phase == 1 && first) break;
        const __hip_bfloat16* Wp = phase ? Whhb : Wihb;
        const int ldk    = phase ? HDIM : FDIM;
        const int nchunk = ldk / BK;
        for (int kc = 0; kc < nchunk; ++kc) {
            __syncthreads();
            #pragma unroll
            for (int g = 0; g < 4; ++g) {
                GLOAD_LDS16(Wp + (size_t)(g * HDIM + j0 + row_ld) * ldk + kc * BK + kh * 8,
                            &sB[(g * 256 + t) * 8]);
            }
            if (phase == 0) {
                // fp32 A: load 8 floats, RNE-pack to bf16, one ds_write_b128
                const float* src = Afp + (size_t)(m0 + row_ld) * ldA + kc * BK + kh * 8;
                const float4 fa = *(const float4*)src;
                const float4 fb = *(const float4*)(src + 4);
                short8 v;
                v[0] = (short)f2bf(fa.x); v[1] = (short)f2bf(fa.y);
                v[2] = (short)f2bf(fa.z); v[3] = (short)f2bf(fa.w);
                v[4] = (short)f2bf(fb.x); v[5] = (short)f2bf(fb.y);
                v[6] = (short)f2bf(fb.z); v[7] = (short)f2bf(fb.w);
                *(short8*)&sA[t * 8] = v;
            } else {
                GLOAD_LDS16(hin + (size_t)(m0 + row_ld) * HDIM + kc * BK + kh * 8, &sA[t * 8]);
            }
            __syncthreads();

            short8 afrag[4];
            #pragma unroll
            for (int mi = 0; mi < 4; ++mi)
                afrag[mi] = *(const short8*)&sA[(mi * 16 + fr) * BK + quad * 8];
            #pragma unroll
            for (int g = 0; g < 4; ++g) {
                short8 bfrag = *(const short8*)&sB[g * BM * BK + (wave * 16 + fr) * BK + quad * 8];
                #pragma unroll
                for (int mi = 0; mi < 4; ++mi)
                    acc[g][mi] = __builtin_amdgcn_mfma_f32_16x16x32_bf16(afrag[mi], bfrag, acc[g][mi], 0, 0, 0);
            }
        }
    }

    // Fused LSTM pointwise epilogue. C/D layout: col=lane&15, row=(lane>>4)*4+reg [m89/m91].
    const int col = j0 + wave * 16 + fr;
    const float bi = bias[col];
    const float bf = bias[HDIM + col];
    const float bg = bias[2 * HDIM + col];
    const float bo = bias[3 * HDIM + col];
    #pragma unroll
    for (int mi = 0; mi < 4; ++mi) {
        #pragma unroll
        for (int r = 0; r < 4; ++r) {
            const int row = m0 + mi * 16 + quad * 4 + r;
            const float iv = acc[0][mi][r] + bi;
            const float fv = acc[1][mi][r] + bf;
            const float gv = acc[2][mi][r] + bg;
            const float ov = acc[3][mi][r] + bo;
            const float cp = first ? 0.0f : cbuf[(size_t)row * HDIM + col];
            const float cn = sigm(fv) * cp + sigm(iv) * tanh_(gv);
            const float hn = sigm(ov) * tanh_(cn);
            cbuf[(size_t)row * HDIM + col] = cn;
            hout[(size_t)row * HDIM + col] = __hip_bfloat16(hn);
        }
    }
}

// out[:, tstep, :] = h @ Wcls^T + b_cls  (fp32 out; next gates step re-reads this slice as A)
__global__ __launch_bounds__(256) void cls_kernel(
    const __hip_bfloat16* __restrict__ h,      // [8192,512] bf16
    const __hip_bfloat16* __restrict__ Wclsb,  // [1024,512] bf16
    const float* __restrict__ bcls,            // [1024] fp32
    float* __restrict__ dout,                  // [8192,8,1024] fp32
    int tstep)
{
    __shared__ __align__(16) __hip_bfloat16 sA[BM * BK];
    __shared__ __align__(16) __hip_bfloat16 sB[BM * BK];

    const int t    = threadIdx.x;
    const int wave = t >> 6;
    const int lane = t & 63;
    const int m0   = blockIdx.x * BM;
    const int n0   = blockIdx.y * 64;

    f32x4 acc[4];
    #pragma unroll
    for (int mi = 0; mi < 4; ++mi) acc[mi] = (f32x4)(0.0f);

    const int row_ld = t >> 2;
    const int kh     = t & 3;
    const int fr     = lane & 15;
    const int quad   = lane >> 4;

    for (int kc = 0; kc < HDIM / BK; ++kc) {
        __syncthreads();
        GLOAD_LDS16(h + (size_t)(m0 + row_ld) * HDIM + kc * BK + kh * 8, &sA[t * 8]);
        GLOAD_LDS16(Wclsb + (size_t)(n0 + row_ld) * HDIM + kc * BK + kh * 8, &sB[t * 8]);
        __syncthreads();

        short8 bfrag = *(const short8*)&sB[(wave * 16 + fr) * BK + quad * 8];
        #pragma unroll
        for (int mi = 0; mi < 4; ++mi) {
            short8 afrag = *(const short8*)&sA[(mi * 16 + fr) * BK + quad * 8];
            acc[mi] = __builtin_amdgcn_mfma_f32_16x16x32_bf16(afrag, bfrag, acc[mi], 0, 0, 0);
        }
    }

    const int col = n0 + wave * 16 + fr;
    const float bc = bcls[col];
    #pragma unroll
    for (int mi = 0; mi < 4; ++mi) {
        #pragma unroll
        for (int r = 0; r < 4; ++r) {
            const int row = m0 + mi * 16 + quad * 4 + r;
            dout[((size_t)row * DSTEPS + tstep) * FDIM + col] = acc[mi][r] + bc;
        }
    }
}

__global__ void cvt_bf16(const float* __restrict__ src, __hip_bfloat16* __restrict__ dst, int n8) {
    int i = blockIdx.x * blockDim.x + threadIdx.x;
    if (i < n8) {
        const float4 a = ((const float4*)src)[2 * i];
        const float4 b = ((const float4*)src)[2 * i + 1];
        short8 v;
        v[0] = (short)f2bf(a.x); v[1] = (short)f2bf(a.y);
        v[2] = (short)f2bf(a.z); v[3] = (short)f2bf(a.w);
        v[4] = (short)f2bf(b.x); v[5] = (short)f2bf(b.y);
        v[6] = (short)f2bf(b.z); v[7] = (short)f2bf(b.w);
        ((short8*)dst)[i] = v;
    }
}

__global__ void prep_bias(const float* __restrict__ bih, const float* __restrict__ bhh,
                          float* __restrict__ bias) {
    int i = blockIdx.x * blockDim.x + threadIdx.x;
    if (i < 4 * HDIM) bias[i] = bih[i] + bhh[i];
}

extern "C" void kernel_launch(void* const* d_in, const int* in_sizes, int n_in,
                              void* d_out, int out_size, void* d_ws, size_t ws_size,
                              hipStream_t stream) {
    const float* x    = (const float*)d_in[0];   // [8192,1024]
    const float* Wih  = (const float*)d_in[1];   // [2048,1024]
    const float* Whh  = (const float*)d_in[2];   // [2048,512]
    const float* bih  = (const float*)d_in[3];   // [2048]
    const float* bhh  = (const float*)d_in[4];   // [2048]
    const float* Wcls = (const float*)d_in[5];   // [1024,512]
    const float* bcls = (const float*)d_in[6];   // [1024]
    float* out = (float*)d_out;                  // [8192,8,1024] fp32

    // Workspace layout (~40 MB total):
    char* ws = (char*)d_ws;
    __hip_bfloat16* Wihb  = (__hip_bfloat16*)(ws);                    // 4 MB
    __hip_bfloat16* Whhb  = (__hip_bfloat16*)(ws + (4ull  << 20));    // 2 MB
    __hip_bfloat16* Wclsb = (__hip_bfloat16*)(ws + (6ull  << 20));    // 1 MB
    float*          bias  = (float*)         (ws + (7ull  << 20));    // 8 KB
    __hip_bfloat16* hbuf0 = (__hip_bfloat16*)(ws + (8ull  << 20));    // 8 MB
    __hip_bfloat16* hbuf1 = (__hip_bfloat16*)(ws + (16ull << 20));    // 8 MB
    float*          cbuf  = (float*)         (ws + (24ull << 20));    // 16 MB

    cvt_bf16<<<dim3(2048 * 1024 / 8 / 256), dim3(256), 0, stream>>>(Wih,  Wihb,  2048 * 1024 / 8);
    cvt_bf16<<<dim3(2048 * 512  / 8 / 256), dim3(256), 0, stream>>>(Whh,  Whhb,  2048 * 512  / 8);
    cvt_bf16<<<dim3(1024 * 512  / 8 / 256), dim3(256), 0, stream>>>(Wcls, Wclsb, 1024 * 512  / 8);
    prep_bias<<<dim3(8), dim3(256), 0, stream>>>(bih, bhh, bias);

    for (int t = 0; t < DSTEPS; ++t) {
        const float* A  = (t == 0) ? x : (out + (size_t)(t - 1) * FDIM);
        const int   ldA = (t == 0) ? FDIM : DSTEPS * FDIM;
        const __hip_bfloat16* hi = (t & 1) ? hbuf0 : hbuf1;  // unused when first=1
        __hip_bfloat16*       ho = (t & 1) ? hbuf1 : hbuf0;
        gates_kernel<<<dim3(M_TOT / BM, HDIM / 64), dim3(256), 0, stream>>>(
            A, ldA, hi, Wihb, Whhb, bias, cbuf, ho, t == 0 ? 1 : 0);
        cls_kernel<<<dim3(M_TOT / BM, FDIM / 64), dim3(256), 0, stream>>>(
            ho, Wclsb, bcls, out, t);
    }
}

// Round 3
// 982.281 us; speedup vs baseline: 1.2625x; 1.2625x over previous
//
#include <hip/hip_runtime.h>
#include <hip/hip_bf16.h>
#include <math.h>

// FutureLSTM: M=8192 independent rows; F=1024; H=512; 4H=2048; D=8 sequential steps.
// fp32 in/out; bf16 MFMA internally. Round 3: BM=128 gates tile, 128x128 cls tile,
// all-bf16 staging via global_load_lds width=16 (fp32->bf16 repack moved out of hot loops).
#define M_TOT 8192
#define FDIM  1024
#define HDIM  512
#define DSTEPS 8
#define BK 32

typedef __attribute__((ext_vector_type(8))) short short8;
typedef __attribute__((ext_vector_type(4))) float f32x4;

#define GLOAD_LDS16(gsrc, ldst)                                                        \
    __builtin_amdgcn_global_load_lds(                                                  \
        (__attribute__((address_space(1))) void*)(void*)(gsrc),                        \
        (__attribute__((address_space(3))) void*)(ldst), 16, 0, 0)

__device__ __forceinline__ unsigned short f2bf(float f) {
    unsigned u = __float_as_uint(f);
    return (unsigned short)((u + 0x7FFFu + ((u >> 16) & 1u)) >> 16);
}
__device__ __forceinline__ float sigm(float x) {
    return __builtin_amdgcn_rcpf(1.0f + __expf(-x));
}
__device__ __forceinline__ float tanh_(float x) {
    // tanh = 1 - 2/(1+e^{2x}); saturates to +/-1, no NaN for finite x.
    return 1.0f - 2.0f * __builtin_amdgcn_rcpf(1.0f + __expf(2.0f * x));
}

// gates = A@Wih^T + h@Whh^T + bias, fused LSTM pointwise -> cbuf (fp32), hout (bf16).
// Block tile: 128 rows x 64 hidden cols x all 4 gates. Wave w owns hidden cols w*16..+15:
// each lane holds i/f/g/o for its (row,col) pairs -> pointwise fused, zero cross-lane traffic.
// Grid 64x8 = 512 blocks = 2 blocks/CU exactly.
__global__ __launch_bounds__(256, 2) void gates_kernel(
    const __hip_bfloat16* __restrict__ Ab,    // [8192,1024] bf16 (xb at t=0, outws after)
    const __hip_bfloat16* __restrict__ hin,   // [8192,512] bf16
    const __hip_bfloat16* __restrict__ Wihb,  // [2048,1024] bf16
    const __hip_bfloat16* __restrict__ Whhb,  // [2048,512] bf16
    const float* __restrict__ bias,           // [2048] fp32 (b_ih+b_hh)
    float* __restrict__ cbuf,                 // [8192,512] fp32 persistent
    __hip_bfloat16* __restrict__ hout,        // [8192,512] bf16
    int first)
{
    __shared__ __align__(16) __hip_bfloat16 sA[128 * BK];      // 8 KB
    __shared__ __align__(16) __hip_bfloat16 sB[4 * 64 * BK];   // 16 KB (4 gate tiles)

    const int t    = threadIdx.x;
    const int wave = t >> 6;
    const int lane = t & 63;
    const int m0   = blockIdx.x * 128;
    const int j0   = blockIdx.y * 64;

    f32x4 acc[4][8];  // [gate][mi] -> 128 VGPRs
    #pragma unroll
    for (int g = 0; g < 4; ++g)
        #pragma unroll
        for (int mi = 0; mi < 8; ++mi) acc[g][mi] = (f32x4)(0.0f);

    const int row_ld = t >> 2;  // 0..63
    const int kh     = t & 3;
    const int fr     = lane & 15;
    const int quad   = lane >> 4;

    for (int phase = 0; phase < 2; ++phase) {
        if (phase == 1 && first) break;
        const __hip_bfloat16* Wp = phase ? Whhb : Wihb;
        const __hip_bfloat16* Ap = phase ? hin : Ab;
        const int ldk    = phase ? HDIM : FDIM;
        const int nchunk = ldk / BK;
        for (int kc = 0; kc < nchunk; ++kc) {
            __syncthreads();
            #pragma unroll
            for (int g = 0; g < 4; ++g) {
                GLOAD_LDS16(Wp + (size_t)(g * HDIM + j0 + row_ld) * ldk + kc * BK + kh * 8,
                            &sB[(g * 256 + t) * 8]);
            }
            GLOAD_LDS16(Ap + (size_t)(m0 + row_ld) * ldk + kc * BK + kh * 8, &sA[t * 8]);
            GLOAD_LDS16(Ap + (size_t)(m0 + 64 + row_ld) * ldk + kc * BK + kh * 8,
                        &sA[2048 + t * 8]);
            __syncthreads();

            short8 bfrag[4];
            #pragma unroll
            for (int g = 0; g < 4; ++g)
                bfrag[g] = *(const short8*)&sB[g * 64 * BK + (wave * 16 + fr) * BK + quad * 8];
            #pragma unroll
            for (int mi = 0; mi < 8; ++mi) {
                short8 afrag = *(const short8*)&sA[(mi * 16 + fr) * BK + quad * 8];
                #pragma unroll
                for (int g = 0; g < 4; ++g)
                    acc[g][mi] = __builtin_amdgcn_mfma_f32_16x16x32_bf16(afrag, bfrag[g], acc[g][mi], 0, 0, 0);
            }
        }
    }

    // Fused LSTM pointwise. C/D layout: col=lane&15, row=(lane>>4)*4+reg [m89/m91].
    const int col = j0 + wave * 16 + fr;
    const float bi = bias[col];
    const float bf = bias[HDIM + col];
    const float bg = bias[2 * HDIM + col];
    const float bo = bias[3 * HDIM + col];
    #pragma unroll
    for (int mi = 0; mi < 8; ++mi) {
        #pragma unroll
        for (int r = 0; r < 4; ++r) {
            const int row = m0 + mi * 16 + quad * 4 + r;
            const float iv = acc[0][mi][r] + bi;
            const float fv = acc[1][mi][r] + bf;
            const float gv = acc[2][mi][r] + bg;
            const float ov = acc[3][mi][r] + bo;
            const float cp = first ? 0.0f : cbuf[(size_t)row * HDIM + col];
            const float cn = sigm(fv) * cp + sigm(iv) * tanh_(gv);
            const float hn = sigm(ov) * tanh_(cn);
            cbuf[(size_t)row * HDIM + col] = cn;
            hout[(size_t)row * HDIM + col] = __hip_bfloat16(hn);
        }
    }
}

// out = h @ Wcls^T + b_cls. 128x128 tile, 4 waves in 2x2, 4x4 16x16 frags per wave.
// Writes fp32 to dout[:, tstep, :] and bf16 to outws (next step's gates A).
__global__ __launch_bounds__(256) void cls_kernel(
    const __hip_bfloat16* __restrict__ h,      // [8192,512] bf16
    const __hip_bfloat16* __restrict__ Wclsb,  // [1024,512] bf16
    const float* __restrict__ bcls,            // [1024] fp32
    float* __restrict__ dout,                  // [8192,8,1024] fp32
    __hip_bfloat16* __restrict__ outws,        // [8192,1024] bf16
    int tstep)
{
    __shared__ __align__(16) __hip_bfloat16 sA[128 * BK];  // 8 KB
    __shared__ __align__(16) __hip_bfloat16 sB[128 * BK];  // 8 KB

    const int t    = threadIdx.x;
    const int wave = t >> 6;
    const int lane = t & 63;
    const int wr   = wave >> 1;  // wave row (0..1)
    const int wc   = wave & 1;   // wave col (0..1)
    const int m0   = blockIdx.x * 128;
    const int n0   = blockIdx.y * 128;

    f32x4 acc[4][4];  // [ni][mi]
    #pragma unroll
    for (int ni = 0; ni < 4; ++ni)
        #pragma unroll
        for (int mi = 0; mi < 4; ++mi) acc[ni][mi] = (f32x4)(0.0f);

    const int row_ld = t >> 2;
    const int kh     = t & 3;
    const int fr     = lane & 15;
    const int quad   = lane >> 4;

    for (int kc = 0; kc < HDIM / BK; ++kc) {
        __syncthreads();
        GLOAD_LDS16(h + (size_t)(m0 + row_ld) * HDIM + kc * BK + kh * 8, &sA[t * 8]);
        GLOAD_LDS16(h + (size_t)(m0 + 64 + row_ld) * HDIM + kc * BK + kh * 8, &sA[2048 + t * 8]);
        GLOAD_LDS16(Wclsb + (size_t)(n0 + row_ld) * HDIM + kc * BK + kh * 8, &sB[t * 8]);
        GLOAD_LDS16(Wclsb + (size_t)(n0 + 64 + row_ld) * HDIM + kc * BK + kh * 8,
                    &sB[2048 + t * 8]);
        __syncthreads();

        short8 afrag[4], bfrag[4];
        #pragma unroll
        for (int i = 0; i < 4; ++i) {
            afrag[i] = *(const short8*)&sA[(wr * 64 + i * 16 + fr) * BK + quad * 8];
            bfrag[i] = *(const short8*)&sB[(wc * 64 + i * 16 + fr) * BK + quad * 8];
        }
        #pragma unroll
        for (int ni = 0; ni < 4; ++ni)
            #pragma unroll
            for (int mi = 0; mi < 4; ++mi)
                acc[ni][mi] = __builtin_amdgcn_mfma_f32_16x16x32_bf16(afrag[mi], bfrag[ni], acc[ni][mi], 0, 0, 0);
    }

    #pragma unroll
    for (int ni = 0; ni < 4; ++ni) {
        const int col = n0 + wc * 64 + ni * 16 + fr;
        const float bc = bcls[col];
        #pragma unroll
        for (int mi = 0; mi < 4; ++mi) {
            #pragma unroll
            for (int r = 0; r < 4; ++r) {
                const int row = m0 + wr * 64 + mi * 16 + quad * 4 + r;
                const float v = acc[ni][mi][r] + bc;
                dout[(size_t)row * (DSTEPS * FDIM) + (size_t)tstep * FDIM + col] = v;
                outws[(size_t)row * FDIM + col] = __hip_bfloat16(v);
            }
        }
    }
}

__global__ void cvt_bf16(const float* __restrict__ src, __hip_bfloat16* __restrict__ dst, int n8) {
    int i = blockIdx.x * blockDim.x + threadIdx.x;
    if (i < n8) {
        const float4 a = ((const float4*)src)[2 * i];
        const float4 b = ((const float4*)src)[2 * i + 1];
        short8 v;
        v[0] = (short)f2bf(a.x); v[1] = (short)f2bf(a.y);
        v[2] = (short)f2bf(a.z); v[3] = (short)f2bf(a.w);
        v[4] = (short)f2bf(b.x); v[5] = (short)f2bf(b.y);
        v[6] = (short)f2bf(b.z); v[7] = (short)f2bf(b.w);
        ((short8*)dst)[i] = v;
    }
}

__global__ void prep_bias(const float* __restrict__ bih, const float* __restrict__ bhh,
                          float* __restrict__ bias) {
    int i = blockIdx.x * blockDim.x + threadIdx.x;
    if (i < 4 * HDIM) bias[i] = bih[i] + bhh[i];
}

extern "C" void kernel_launch(void* const* d_in, const int* in_sizes, int n_in,
                              void* d_out, int out_size, void* d_ws, size_t ws_size,
                              hipStream_t stream) {
    const float* x    = (const float*)d_in[0];   // [8192,1024]
    const float* Wih  = (const float*)d_in[1];   // [2048,1024]
    const float* Whh  = (const float*)d_in[2];   // [2048,512]
    const float* bih  = (const float*)d_in[3];   // [2048]
    const float* bhh  = (const float*)d_in[4];   // [2048]
    const float* Wcls = (const float*)d_in[5];   // [1024,512]
    const float* bcls = (const float*)d_in[6];   // [1024]
    float* out = (float*)d_out;                  // [8192,8,1024] fp32

    // Workspace layout (~71 MB):
    char* ws = (char*)d_ws;
    __hip_bfloat16* Wihb  = (__hip_bfloat16*)(ws);                    //  4 MB
    __hip_bfloat16* Whhb  = (__hip_bfloat16*)(ws + (4ull  << 20));    //  2 MB
    __hip_bfloat16* Wclsb = (__hip_bfloat16*)(ws + (6ull  << 20));    //  1 MB
    float*          bias  = (float*)         (ws + (7ull  << 20));    //  8 KB
    __hip_bfloat16* xb    = (__hip_bfloat16*)(ws + (8ull  << 20));    // 16 MB
    __hip_bfloat16* outws = (__hip_bfloat16*)(ws + (24ull << 20));    // 16 MB
    __hip_bfloat16* hbuf0 = (__hip_bfloat16*)(ws + (40ull << 20));    //  8 MB
    __hip_bfloat16* hbuf1 = (__hip_bfloat16*)(ws + (48ull << 20));    //  8 MB
    float*          cbuf  = (float*)         (ws + (56ull << 20));    // 16 MB

    cvt_bf16<<<dim3(2048 * 1024 / 8 / 256), dim3(256), 0, stream>>>(Wih,  Wihb,  2048 * 1024 / 8);
    cvt_bf16<<<dim3(2048 * 512  / 8 / 256), dim3(256), 0, stream>>>(Whh,  Whhb,  2048 * 512  / 8);
    cvt_bf16<<<dim3(1024 * 512  / 8 / 256), dim3(256), 0, stream>>>(Wcls, Wclsb, 1024 * 512  / 8);
    cvt_bf16<<<dim3(8192 * 1024 / 8 / 256), dim3(256), 0, stream>>>(x,    xb,    8192 * 1024 / 8);
    prep_bias<<<dim3(8), dim3(256), 0, stream>>>(bih, bhh, bias);

    for (int t = 0; t < DSTEPS; ++t) {
        const __hip_bfloat16* A  = (t == 0) ? xb : outws;
        const __hip_bfloat16* hi = (t & 1) ? hbuf0 : hbuf1;  // unused when first=1
        __hip_bfloat16*       ho = (t & 1) ? hbuf1 : hbuf0;
        gates_kernel<<<dim3(M_TOT / 128, HDIM / 64), dim3(256), 0, stream>>>(
            A, hi, Wihb, Whhb, bias, cbuf, ho, t == 0 ? 1 : 0);
        cls_kernel<<<dim3(M_TOT / 128, FDIM / 128), dim3(256), 0, stream>>>(
            ho, Wclsb, bcls, out, outws, t);
    }
}